// Round 1
// baseline (3057.254 us; speedup 1.0000x reference)
//
#include <hip/hip_runtime.h>
#include <cstddef>

typedef unsigned short ushort_t;
typedef __attribute__((ext_vector_type(8))) short bf16x8;
typedef __attribute__((ext_vector_type(4))) float f32x4;

#define Bb 256
#define Hh 1024
#define Ff 512
#define Tt 128

// ---------- helpers ----------
__device__ __forceinline__ ushort_t f2bf(float f) {
    unsigned int u = __float_as_uint(f);
    unsigned int r = (u + 0x7FFFu + ((u >> 16) & 1u)) >> 16;
    return (ushort_t)r;
}
__device__ __forceinline__ float sigf(float x)  { return 1.0f / (1.0f + __expf(-x)); }
__device__ __forceinline__ float tanhf_(float x){ return 2.0f / (1.0f + __expf(-2.0f * x)) - 1.0f; }

// ---------- weight swizzle: row-major fp32 [K][N] -> bf16 B-fragment blocks ----------
// Block layout: [ntile = n/16][kstep = k/32] of 1KB blocks.
// Within a block: lane = (koff/8)*16 + (n%16), j = koff%8; byte = lane*16 + j*2.
// mode 0: bf16(s0[k][n] + s1[k][n])          (Msum = W+U, K=1024)
// mode 1: bf16(k<1024 ? s0[k][n] : s1[k-1024][n])  (Mcat = [W;U], K=2048)
// mode 2: bf16(s0[k][n])                     (Wd, K=1024, N=512)
__global__ void swz(const float* __restrict__ s0, const float* __restrict__ s1,
                    ushort_t* __restrict__ dst, int K, int N, int mode, int total)
{
    int KB = K >> 5;
    for (int idx = blockIdx.x * blockDim.x + threadIdx.x; idx < total;
         idx += gridDim.x * blockDim.x) {
        int blk   = idx >> 9;
        int lane  = (idx >> 3) & 63;
        int j     = idx & 7;
        int ntile = blk / KB;
        int kstep = blk - ntile * KB;
        int n = (ntile << 4) + (lane & 15);
        int k = (kstep << 5) + ((lane >> 4) << 3) + j;
        float v;
        if (mode == 0)      v = s0[(size_t)k * N + n] + s1[(size_t)k * N + n];
        else if (mode == 1) v = (k < 1024) ? s0[(size_t)k * N + n]
                                           : s1[(size_t)(k - 1024) * N + n];
        else                v = s0[(size_t)k * N + n];
        dst[idx] = f2bf(v);
    }
}

// ---------- A0 = [x0 | h0] as bf16, plain row-major [256][2048] ----------
__global__ void mk_a0(const float* __restrict__ x0, const float* __restrict__ h0,
                      ushort_t* __restrict__ a0)
{
    int idx = blockIdx.x * blockDim.x + threadIdx.x;
    if (idx >= Bb * 2048) return;
    int r = idx >> 11, k = idx & 2047;
    float v = (k < 1024) ? x0[r * 1024 + k] : h0[r * 1024 + k - 1024];
    a0[idx] = f2bf(v);
}

__global__ void zero_cnt(int* cnt) {
    int i = blockIdx.x * blockDim.x + threadIdx.x;
    if (i < Tt * 4) cnt[i] = 0;
}

// ---------- persistent LSTM scan ----------
// grid = 256 WGs (1/CU), block = 256 (4 waves).
// WG tile: 64 batch rows x (16 h-units x 4 gates = 64 z-cols).
// wave (wr,wc) computes 32x32 of the 64x64 z tile via 2x2 MFMA 16x16x32 bf16.
// Per-btile flag barrier: consumers of seq[t-1] rows wait until all 64 WGs of
// that btile have published (device-scope atomics, guide G16).
__launch_bounds__(256, 2)
__global__ void lstm_steps(const ushort_t* __restrict__ A0,
                           const ushort_t* __restrict__ Mcat,
                           const ushort_t* __restrict__ Msum,
                           const float* __restrict__ bias,
                           const float* __restrict__ c0,
                           ushort_t* __restrict__ seq,
                           int* __restrict__ cnt)
{
    // LDS: fragment-ordered staging buffers + fp32 z exchange
    __shared__ __align__(16) ushort_t lA[4 * 4 * 64 * 8];  // [kk4][msub4][lane64][8] 16KB
    __shared__ __align__(16) ushort_t lB[4 * 4 * 64 * 8];  // [kk4][csub4][lane64][8] 16KB
    __shared__ float lZ[64 * 68];                           // 64 rows x 64 cols (+4 pad)

    const int tid  = threadIdx.x;
    const int w    = tid >> 6, lane = tid & 63;
    const int wg   = blockIdx.x;
    // XCD swizzle: same btile -> XCD pair {2bt,2bt+1} for A-slice L2 locality
    const int bt = (wg & 7) >> 1;                   // 0..3 : 64-row batch tile
    const int ht = ((wg >> 3) << 1) | (wg & 1);     // 0..63: 16-unit h tile
    const int r0 = bt << 6;
    const int hb = ht << 4;
    const int wr = w >> 1, wc = w & 1;

    float c_reg[4];  // c-state: cell i = (row=(i*256+tid)>>4, u=(i*256+tid)&15), fixed per step

    for (int t = 0; t < Tt; ++t) {
        const ushort_t* Ap; const ushort_t* Bw; int KB;
        if (t == 0) { Ap = A0; Bw = Mcat; KB = 64; }
        else        { Ap = seq + (size_t)(t - 1) * Bb * Hh; Bw = Msum; KB = 32; }
        const int K = KB << 5;

        if (t > 0) {
            if (tid == 0) {
                int iter = 0;
                while (__hip_atomic_load(&cnt[((t - 1) << 2) + bt], __ATOMIC_ACQUIRE,
                                         __HIP_MEMORY_SCOPE_AGENT) < 64 &&
                       iter < 100000) ++iter;  // capped: misbehavior -> wrong, not hung
            }
            __syncthreads();
        }

        f32x4 acc[2][2];
        #pragma unroll
        for (int m = 0; m < 2; ++m)
            #pragma unroll
            for (int n = 0; n < 2; ++n) acc[m][n] = (f32x4){0.f, 0.f, 0.f, 0.f};

        for (int kc = 0; kc < K; kc += 128) {
            // stage A (64 rows x 128 k): 1024 x 16B pieces, 4/thread, swizzle-on-write
            #pragma unroll
            for (int i = 0; i < 4; ++i) {
                int p = (i << 8) + tid;
                int row = p >> 4, kp = p & 15;
                bf16x8 v = *(const bf16x8*)(Ap + (size_t)(r0 + row) * K + kc + (kp << 3));
                int kk = kp >> 2, q = kp & 3, msub = row >> 4, mm = row & 15;
                *(bf16x8*)&lA[((((kk << 2) + msub) << 6) + (q << 4) + mm) << 3] = v;
            }
            // stage B (4 gate-ntiles x 128 k): already fragment-ordered in global
            #pragma unroll
            for (int i = 0; i < 4; ++i) {
                int d = (i << 8) + tid;              // linear dest piece
                int kk = d >> 8, csub = (d >> 6) & 3, ln = d & 63;
                int nt = (csub << 6) + ht;           // gate csub, ntile within gate = ht
                bf16x8 v = *(const bf16x8*)(Bw + (((size_t)(nt * KB + (kc >> 5) + kk)) << 9) + (ln << 3));
                *(bf16x8*)&lB[d << 3] = v;
            }
            __syncthreads();
            #pragma unroll
            for (int kk = 0; kk < 4; ++kk) {
                bf16x8 af[2], bfr[2];
                #pragma unroll
                for (int m = 0; m < 2; ++m)
                    af[m] = *(const bf16x8*)&lA[((((kk << 2) + (wr << 1) + m) << 6) + lane) << 3];
                #pragma unroll
                for (int n = 0; n < 2; ++n)
                    bfr[n] = *(const bf16x8*)&lB[((((kk << 2) + (wc << 1) + n) << 6) + lane) << 3];
                #pragma unroll
                for (int m = 0; m < 2; ++m)
                    #pragma unroll
                    for (int n = 0; n < 2; ++n)
                        acc[m][n] = __builtin_amdgcn_mfma_f32_16x16x32_bf16(
                            af[m], bfr[n], acc[m][n], 0, 0, 0);
            }
            __syncthreads();
        }

        // epilogue: C/D layout col=lane&15, row=quad*4+reg (m89-verified)
        {
            int q = lane >> 4, nl = lane & 15;
            #pragma unroll
            for (int m = 0; m < 2; ++m)
                #pragma unroll
                for (int n = 0; n < 2; ++n)
                    #pragma unroll
                    for (int r = 0; r < 4; ++r)
                        lZ[((wr << 5) + (m << 4) + (q << 2) + r) * 68 +
                           (wc << 5) + (n << 4) + nl] = acc[m][n][r];
        }
        __syncthreads();

        // gates (Keras order i,f,g,o) + c/h update; h -> seq[t] bf16
        #pragma unroll
        for (int i = 0; i < 4; ++i) {
            int idx = (i << 8) + tid;
            int row = idx >> 4, u = idx & 15;
            float zi = lZ[row * 68 +      u] + bias[       hb + u];
            float zf = lZ[row * 68 + 16 + u] + bias[1024 + hb + u];
            float zg = lZ[row * 68 + 32 + u] + bias[2048 + hb + u];
            float zo = lZ[row * 68 + 48 + u] + bias[3072 + hb + u];
            float cp = (t == 0) ? c0[(size_t)(r0 + row) * Hh + hb + u] : c_reg[i];
            float cn = sigf(zf) * cp + sigf(zi) * tanhf_(zg);
            float hn = sigf(zo) * tanhf_(cn);
            c_reg[i] = cn;
            seq[(size_t)t * Bb * Hh + (size_t)(r0 + row) * Hh + hb + u] = f2bf(hn);
        }
        __syncthreads();  // all seq[t] stores drained (syncthreads implies vmcnt(0))
        if (tid == 0) {
            __threadfence();  // device-scope release (flush XCD L2 path)
            __hip_atomic_fetch_add(&cnt[(t << 2) + bt], 1, __ATOMIC_RELEASE,
                                   __HIP_MEMORY_SCOPE_AGENT);
        }
    }
}

// ---------- batched emission: out[b][t][f] = seq_flat[(t*256+b)][:] @ Wd + bd ----------
// WG tile 128x128, 4 waves each 64x64 (4x4 MFMA blocking). grid (256,4).
__launch_bounds__(256, 2)
__global__ void emit(const ushort_t* __restrict__ seq,   // [32768][1024] bf16 row-major
                     const ushort_t* __restrict__ Wsw,   // swizzled, KB=32, 32 ntiles
                     const float* __restrict__ bd,
                     float* __restrict__ out)
{
    __shared__ __align__(16) ushort_t lA[2 * 8 * 64 * 8];  // [kk2][msub8][lane][8] 16KB
    __shared__ __align__(16) ushort_t lB[2 * 8 * 64 * 8];  // [kk2][csub8][lane][8] 16KB
    const int tid = threadIdx.x, w = tid >> 6, lane = tid & 63;
    const int rt = blockIdx.x, ct = blockIdx.y;
    const int r0 = rt << 7, f0 = ct << 7;
    const int wr = w >> 1, wc = w & 1;

    f32x4 acc[4][4];
    #pragma unroll
    for (int m = 0; m < 4; ++m)
        #pragma unroll
        for (int n = 0; n < 4; ++n) acc[m][n] = (f32x4){0.f, 0.f, 0.f, 0.f};

    for (int kc = 0; kc < Hh; kc += 64) {
        #pragma unroll
        for (int i = 0; i < 4; ++i) {               // A: 128 rows x 8 kp = 1024 pieces
            int p = (i << 8) + tid;
            int row = p >> 3, kp = p & 7;
            bf16x8 v = *(const bf16x8*)(seq + (size_t)(r0 + row) * Hh + kc + (kp << 3));
            int kk = kp >> 2, q = kp & 3, msub = row >> 4, mm = row & 15;
            *(bf16x8*)&lA[((((kk << 3) + msub) << 6) + (q << 4) + mm) << 3] = v;
        }
        #pragma unroll
        for (int i = 0; i < 4; ++i) {               // B: 8 ntiles x kk2 = 1024 pieces
            int d = (i << 8) + tid;
            int kk = d >> 9, csub = (d >> 6) & 7, ln = d & 63;
            int nt = (ct << 3) + csub;
            bf16x8 v = *(const bf16x8*)(Wsw + (((size_t)(nt * 32 + (kc >> 5) + kk)) << 9) + (ln << 3));
            *(bf16x8*)&lB[d << 3] = v;
        }
        __syncthreads();
        #pragma unroll
        for (int kk = 0; kk < 2; ++kk) {
            bf16x8 af[4], bfr[4];
            #pragma unroll
            for (int m = 0; m < 4; ++m)
                af[m] = *(const bf16x8*)&lA[((((kk << 3) + (wr << 2) + m) << 6) + lane) << 3];
            #pragma unroll
            for (int n = 0; n < 4; ++n)
                bfr[n] = *(const bf16x8*)&lB[((((kk << 3) + (wc << 2) + n) << 6) + lane) << 3];
            #pragma unroll
            for (int m = 0; m < 4; ++m)
                #pragma unroll
                for (int n = 0; n < 4; ++n)
                    acc[m][n] = __builtin_amdgcn_mfma_f32_16x16x32_bf16(
                        af[m], bfr[n], acc[m][n], 0, 0, 0);
        }
        __syncthreads();
    }

    int q = lane >> 4, nl = lane & 15;
    float bdv[4];
    #pragma unroll
    for (int n = 0; n < 4; ++n) bdv[n] = bd[f0 + (wc << 6) + (n << 4) + nl];
    #pragma unroll
    for (int m = 0; m < 4; ++m)
        #pragma unroll
        for (int r = 0; r < 4; ++r) {
            int grow = r0 + (wr << 6) + (m << 4) + (q << 2) + r;  // = t*256 + b
            int tt = grow >> 8, bb = grow & 255;
            float* op = out + ((size_t)((bb << 7) + tt) << 9);
            #pragma unroll
            for (int n = 0; n < 4; ++n)
                op[f0 + (wc << 6) + (n << 4) + nl] = acc[m][n][r] + bdv[n];
        }
}

// ---------- launch ----------
extern "C" void kernel_launch(void* const* d_in, const int* in_sizes, int n_in,
                              void* d_out, int out_size, void* d_ws, size_t ws_size,
                              hipStream_t stream)
{
    const float* x0 = (const float*)d_in[0];
    const float* h0 = (const float*)d_in[1];
    const float* c0 = (const float*)d_in[2];
    const float* W  = (const float*)d_in[3];
    const float* U  = (const float*)d_in[4];
    const float* b  = (const float*)d_in[5];
    const float* Wd = (const float*)d_in[6];
    const float* bd = (const float*)d_in[7];
    float* out = (float*)d_out;

    // workspace layout (bytes)
    const size_t OFF_MCAT = 0;                  // 2048*4096*2 = 16,777,216
    const size_t OFF_MSUM = 16777216;           //  8,388,608
    const size_t OFF_WSW  = 25165824;           //  1,048,576
    const size_t OFF_A0   = 26214400;           //  1,048,576
    const size_t OFF_SEQ  = 27262976;           // 67,108,864
    const size_t OFF_CNT  = 94371840;           //      2,048
    const size_t WS_NEED  = 94373888;
    if (ws_size < WS_NEED) return;              // diagnosable failure, not OOB writes

    char* ws = (char*)d_ws;
    ushort_t* Mcat = (ushort_t*)(ws + OFF_MCAT);
    ushort_t* Msum = (ushort_t*)(ws + OFF_MSUM);
    ushort_t* Wsw  = (ushort_t*)(ws + OFF_WSW);
    ushort_t* A0   = (ushort_t*)(ws + OFF_A0);
    ushort_t* seq  = (ushort_t*)(ws + OFF_SEQ);
    int*      cnt  = (int*)(ws + OFF_CNT);

    zero_cnt<<<2, 256, 0, stream>>>(cnt);
    mk_a0<<<2048, 256, 0, stream>>>(x0, h0, A0);
    swz<<<4096, 256, 0, stream>>>(W, U, Mcat, 2048, 4096, 1, 2048 * 4096);
    swz<<<2048, 256, 0, stream>>>(W, U, Msum, 1024, 4096, 0, 1024 * 4096);
    swz<<<512, 256, 0, stream>>>(Wd, nullptr, Wsw, 1024, 512, 2, 1024 * 512);
    lstm_steps<<<256, 256, 0, stream>>>(A0, Mcat, Msum, b, c0, seq, cnt);
    emit<<<dim3(256, 4), 256, 0, stream>>>(seq, Wsw, bd, out);
}

// Round 2
// 1281.560 us; speedup vs baseline: 2.3856x; 2.3856x over previous
//
#include <hip/hip_runtime.h>
#include <cstddef>
#include <cstdint>

typedef unsigned short ushort_t;
typedef __attribute__((ext_vector_type(8))) short bf16x8;
typedef __attribute__((ext_vector_type(4))) float f32x4;

#define Bb 256
#define Hh 1024
#define Ff 512
#define Tt 128

// ---------- helpers ----------
__device__ __forceinline__ ushort_t f2bf(float f) {
    unsigned int u = __float_as_uint(f);
    unsigned int r = (u + 0x7FFFu + ((u >> 16) & 1u)) >> 16;
    return (ushort_t)r;
}
__device__ __forceinline__ float sigf(float x)  { return 1.0f / (1.0f + __expf(-x)); }
__device__ __forceinline__ float tanhf_(float x){ return 2.0f / (1.0f + __expf(-2.0f * x)) - 1.0f; }

// ---------- weight swizzle: row-major fp32 [K][N] -> bf16 B-fragment blocks ----------
// 1KB blocks indexed [ntile][kstep]; within: lane=(koff/8)*16+(n%16), j=koff%8.
// modes 0 (Msum=W+U) and 1 (Mcat=[W;U]) use GATE-INTERLEAVED ntile order:
//   ntile = ugroup*4 + gate ; source col n = gate*1024 + ugroup*16 + (n%16)
// so a 64-col tile (4 consecutive ntiles) = {i,f,g,o} x 16 h-units.
// mode 2 (Wd): plain ntile = n/16 (emit kernel depends on this).
__global__ void swz(const float* __restrict__ s0, const float* __restrict__ s1,
                    ushort_t* __restrict__ dst, int K, int N, int mode, int total)
{
    int KB = K >> 5;
    for (int idx = blockIdx.x * blockDim.x + threadIdx.x; idx < total;
         idx += gridDim.x * blockDim.x) {
        int blk   = idx >> 9;
        int lane  = (idx >> 3) & 63;
        int j     = idx & 7;
        int ntile = blk / KB;
        int kstep = blk - ntile * KB;
        int k = (kstep << 5) + ((lane >> 4) << 3) + j;
        int n;
        if (mode == 2) n = (ntile << 4) + (lane & 15);
        else           n = ((ntile & 3) << 10) + ((ntile >> 2) << 4) + (lane & 15);
        float v;
        if (mode == 0)      v = s0[(size_t)k * N + n] + s1[(size_t)k * N + n];
        else if (mode == 1) v = (k < 1024) ? s0[(size_t)k * N + n]
                                           : s1[(size_t)(k - 1024) * N + n];
        else                v = s0[(size_t)k * N + n];
        dst[idx] = f2bf(v);
    }
}

// ---------- A0 = [x0 | h0] as bf16, row-major [256][2048] ----------
__global__ void mk_a0(const float* __restrict__ x0, const float* __restrict__ h0,
                      ushort_t* __restrict__ a0)
{
    int idx = blockIdx.x * blockDim.x + threadIdx.x;
    if (idx >= Bb * 2048) return;
    int r = idx >> 11, k = idx & 2047;
    float v = (k < 1024) ? x0[r * 1024 + k] : h0[r * 1024 + k - 1024];
    a0[idx] = f2bf(v);
}

// ---------- one LSTM step: z = h_prev @ Bw ; gates ; c,h update ----------
// grid = 256 blocks (1/CU), block = 256 (4 waves). Tile: 64 batch x 64 z-cols
// (= 4 gates x 16 h-units, thanks to gate-interleaved B order).
// Block-id swizzle: id%8 (presumed XCD) owns ntg in {8k..8k+7} for all 4 bts,
// so each XCD's Msum slice refetch after the kernel-boundary L2 inv is ~1 MB.
// A-staging LDS writes use an XOR bank swizzle (store footprint was 4 banks,
// SQ_LDS_BANK_CONFLICT=2.4e8 in round 1); reads apply the same XOR.
__global__ __launch_bounds__(256) void lstm_step(
    const ushort_t* __restrict__ Ap, int K,
    const ushort_t* __restrict__ Bw,
    const float* cin, float* cout,          // no __restrict__: may alias (in-place c)
    ushort_t* __restrict__ seqt,
    const float* __restrict__ bias)
{
    __shared__ __align__(16) ushort_t lA[32 * 512];   // 32 KB: blocks [kk*4+msub]
    __shared__ __align__(16) ushort_t lB[32 * 512];   // 32 KB: blocks [kk*4+nsub]

    const int tid = threadIdx.x, w = tid >> 6, lane = tid & 63;
    const int id = blockIdx.x;
    const int ntg = ((id & 7) << 3) | (id >> 5);   // 0..63
    const int bt  = (id >> 3) & 3;                 // 0..3
    const int r0 = bt << 6, hb = ntg << 4;
    const int wr = w >> 1, wc = w & 1;
    const int KB = K >> 5;

    f32x4 acc[2][2];
    #pragma unroll
    for (int m = 0; m < 2; ++m)
        #pragma unroll
        for (int n = 0; n < 2; ++n) acc[m][n] = (f32x4){0.f, 0.f, 0.f, 0.f};

    const int kp = tid & 31;             // A piece-in-row: k-chunk position
    const int q_a = kp & 3, kk_a = kp >> 2;

    for (int kc = 0; kc < K; kc += 256) {
        // A: 64 rows x 256 k = 2048 x 16B pieces, 8/thread; coalesced rows
        bf16x8 va[8];
        #pragma unroll
        for (int i = 0; i < 8; ++i) {
            int row = (i << 3) + (tid >> 5);
            va[i] = *(const bf16x8*)(Ap + (size_t)(r0 + row) * K + kc + (kp << 3));
        }
        // B: 4 ntiles x 8 ksteps of pre-swizzled 1KB blocks, straight copy
        bf16x8 vb[8];
        #pragma unroll
        for (int i = 0; i < 8; ++i)
            vb[i] = *(const bf16x8*)(Bw +
                ((((size_t)((ntg << 2) + w)) * KB + (kc >> 5) + i) << 9) + (lane << 3));
        // stores (XOR bank swizzle on A)
        #pragma unroll
        for (int i = 0; i < 8; ++i) {
            int row = (i << 3) + (tid >> 5);
            int msub = row >> 4, mm = row & 15;
            int pos = (q_a << 4) | (mm ^ (((kk_a << 2) + q_a) & 15));
            *(bf16x8*)&lA[((((kk_a << 2) + msub) << 6) + pos) << 3] = va[i];
        }
        #pragma unroll
        for (int i = 0; i < 8; ++i)
            *(bf16x8*)&lB[(((i << 2) + w) << 9) + (lane << 3)] = vb[i];
        __syncthreads();

        #pragma unroll
        for (int kk = 0; kk < 8; ++kk) {
            const int qq = lane >> 4, mm = lane & 15;
            const int pos = (qq << 4) | (mm ^ (((kk << 2) + qq) & 15));
            bf16x8 af[2], bfr[2];
            #pragma unroll
            for (int m = 0; m < 2; ++m)
                af[m] = *(const bf16x8*)&lA[((((kk << 2) + (wr << 1) + m) << 6) + pos) << 3];
            #pragma unroll
            for (int n = 0; n < 2; ++n)
                bfr[n] = *(const bf16x8*)&lB[((((kk << 2) + (wc << 1) + n) << 6) + lane) << 3];
            #pragma unroll
            for (int m = 0; m < 2; ++m)
                #pragma unroll
                for (int n = 0; n < 2; ++n)
                    acc[m][n] = __builtin_amdgcn_mfma_f32_16x16x32_bf16(
                        af[m], bfr[n], acc[m][n], 0, 0, 0);
        }
        __syncthreads();
    }

    // z exchange via LDS (reuse lA: 64x68 fp32 = 17.4 KB)
    float* lZ = (float*)lA;
    {
        int q = lane >> 4, nl = lane & 15;
        #pragma unroll
        for (int m = 0; m < 2; ++m)
            #pragma unroll
            for (int n = 0; n < 2; ++n)
                #pragma unroll
                for (int r = 0; r < 4; ++r)
                    lZ[((wr << 5) + (m << 4) + (q << 2) + r) * 68 +
                       (wc << 5) + (n << 4) + nl] = acc[m][n][r];
    }
    __syncthreads();

    // gates (cols 0..15=i, 16..31=f, 32..47=g, 48..63=o), c/h update
    #pragma unroll
    for (int i = 0; i < 4; ++i) {
        int idx = (i << 8) + tid;
        int row = idx >> 4, u = idx & 15;
        float zi = lZ[row * 68 +      u] + bias[       hb + u];
        float zf = lZ[row * 68 + 16 + u] + bias[1024 + hb + u];
        float zg = lZ[row * 68 + 32 + u] + bias[2048 + hb + u];
        float zo = lZ[row * 68 + 48 + u] + bias[3072 + hb + u];
        size_t cidx = (size_t)(r0 + row) * Hh + hb + u;
        float cp = cin[cidx];
        float cn = sigf(zf) * cp + sigf(zi) * tanhf_(zg);
        cout[cidx] = cn;
        seqt[cidx] = f2bf(sigf(zo) * tanhf_(cn));
    }
}

// ---------- batched emission: out[b][t][f] = seq_flat[(t*256+b)][:] @ Wd + bd ----------
__global__ __launch_bounds__(256) void emit(
    const ushort_t* __restrict__ seq,   // [32768][1024] bf16 row-major
    const ushort_t* __restrict__ Wsw,   // swizzled (mode 2), KB=32, 32 ntiles
    const float* __restrict__ bd,
    float* __restrict__ out)
{
    __shared__ __align__(16) ushort_t lA[2 * 8 * 64 * 8];
    __shared__ __align__(16) ushort_t lB[2 * 8 * 64 * 8];
    const int tid = threadIdx.x, w = tid >> 6, lane = tid & 63;
    const int rt = blockIdx.x, ct = blockIdx.y;
    const int r0 = rt << 7, f0 = ct << 7;
    const int wr = w >> 1, wc = w & 1;

    f32x4 acc[4][4];
    #pragma unroll
    for (int m = 0; m < 4; ++m)
        #pragma unroll
        for (int n = 0; n < 4; ++n) acc[m][n] = (f32x4){0.f, 0.f, 0.f, 0.f};

    for (int kc = 0; kc < Hh; kc += 64) {
        #pragma unroll
        for (int i = 0; i < 4; ++i) {
            int p = (i << 8) + tid;
            int row = p >> 3, kpp = p & 7;
            bf16x8 v = *(const bf16x8*)(seq + (size_t)(r0 + row) * Hh + kc + (kpp << 3));
            int kk = kpp >> 2, q = kpp & 3, msub = row >> 4, mm = row & 15;
            *(bf16x8*)&lA[((((kk << 3) + msub) << 6) + (q << 4) + mm) << 3] = v;
        }
        #pragma unroll
        for (int i = 0; i < 4; ++i) {
            int d = (i << 8) + tid;
            int kk = d >> 9, csub = (d >> 6) & 7, ln = d & 63;
            int nt = (ct << 3) + csub;
            bf16x8 v = *(const bf16x8*)(Wsw + (((size_t)(nt * 32 + (kc >> 5) + kk)) << 9) + (ln << 3));
            *(bf16x8*)&lB[d << 3] = v;
        }
        __syncthreads();
        #pragma unroll
        for (int kk = 0; kk < 2; ++kk) {
            bf16x8 af[4], bfr[4];
            #pragma unroll
            for (int m = 0; m < 4; ++m)
                af[m] = *(const bf16x8*)&lA[((((kk << 3) + (wr << 2) + m) << 6) + lane) << 3];
            #pragma unroll
            for (int n = 0; n < 4; ++n)
                bfr[n] = *(const bf16x8*)&lB[((((kk << 3) + (wc << 2) + n) << 6) + lane) << 3];
            #pragma unroll
            for (int m = 0; m < 4; ++m)
                #pragma unroll
                for (int n = 0; n < 4; ++n)
                    acc[m][n] = __builtin_amdgcn_mfma_f32_16x16x32_bf16(
                        af[m], bfr[n], acc[m][n], 0, 0, 0);
        }
        __syncthreads();
    }

    int q = lane >> 4, nl = lane & 15;
    float bdv[4];
    #pragma unroll
    for (int n = 0; n < 4; ++n) bdv[n] = bd[f0 + (wc << 6) + (n << 4) + nl];
    #pragma unroll
    for (int m = 0; m < 4; ++m)
        #pragma unroll
        for (int r = 0; r < 4; ++r) {
            int grow = r0 + (wr << 6) + (m << 4) + (q << 2) + r;  // = t*256 + b
            int tt = grow >> 8, bb = grow & 255;
            float* op = out + ((size_t)((bb << 7) + tt) << 9);
            #pragma unroll
            for (int n = 0; n < 4; ++n)
                op[f0 + (wc << 6) + (n << 4) + nl] = acc[m][n][r] + bdv[n];
        }
}

// ---------- launch ----------
extern "C" void kernel_launch(void* const* d_in, const int* in_sizes, int n_in,
                              void* d_out, int out_size, void* d_ws, size_t ws_size,
                              hipStream_t stream)
{
    const float* x0 = (const float*)d_in[0];
    const float* h0 = (const float*)d_in[1];
    const float* c0 = (const float*)d_in[2];
    const float* W  = (const float*)d_in[3];
    const float* U  = (const float*)d_in[4];
    const float* b  = (const float*)d_in[5];
    const float* Wd = (const float*)d_in[6];
    const float* bd = (const float*)d_in[7];
    float* out = (float*)d_out;

    // workspace layout (bytes)
    const size_t OFF_MCAT = 0;                  // 16,777,216
    const size_t OFF_MSUM = 16777216;           //  8,388,608
    const size_t OFF_WSW  = 25165824;           //  1,048,576
    const size_t OFF_A0   = 26214400;           //  1,048,576
    const size_t OFF_SEQ  = 27262976;           // 67,108,864
    const size_t WS_NEED  = 94371840;
    if (ws_size < WS_NEED) return;

    char* ws = (char*)d_ws;
    ushort_t* Mcat = (ushort_t*)(ws + OFF_MCAT);
    ushort_t* Msum = (ushort_t*)(ws + OFF_MSUM);
    ushort_t* Wsw  = (ushort_t*)(ws + OFF_WSW);
    ushort_t* A0   = (ushort_t*)(ws + OFF_A0);
    ushort_t* seq  = (ushort_t*)(ws + OFF_SEQ);
    // c-state: first 1 MB of d_out (dead by emit time; emit overwrites all of out)
    float* cws = out;

    mk_a0<<<2048, 256, 0, stream>>>(x0, h0, A0);
    swz<<<4096, 256, 0, stream>>>(W, U, Mcat, 2048, 4096, 1, 2048 * 4096);
    swz<<<2048, 256, 0, stream>>>(W, U, Msum, 1024, 4096, 0, 1024 * 4096);
    swz<<<512, 256, 0, stream>>>(Wd, nullptr, Wsw, 1024, 512, 2, 1024 * 512);

    lstm_step<<<256, 256, 0, stream>>>(A0, 2048, Mcat, c0, cws, seq, b);
    for (int t = 1; t < Tt; ++t)
        lstm_step<<<256, 256, 0, stream>>>(seq + (size_t)(t - 1) * Bb * Hh, 1024, Msum,
                                           cws, cws, seq + (size_t)t * Bb * Hh, b);

    emit<<<dim3(256, 4), 256, 0, stream>>>(seq, Wsw, bd, out);
}